// Round 9
// baseline (185.065 us; speedup 1.0000x reference)
//
#include <hip/hip_runtime.h>
#include <stdint.h>
#include <math.h>

#define BB 2
#define SS 2048
#define DM 1024
#define NH 16
#define HD 64
#define MTOT (BB*SS)

typedef __bf16 bf16x8 __attribute__((ext_vector_type(8)));
typedef float  f32x4  __attribute__((ext_vector_type(4)));
typedef uint32_t u32x4 __attribute__((ext_vector_type(4)));

__device__ __forceinline__ unsigned short f2bf(float f) {
  __bf16 h = (__bf16)f;                 // RNE; compiler packs to v_cvt_pk_bf16_f32
  return __builtin_bit_cast(unsigned short, h);
}

__device__ __forceinline__ bf16x8 ldsv8(const unsigned short* p) {
  return __builtin_bit_cast(bf16x8, *(const u32x4*)p);
}

__device__ __forceinline__ void gl16(const void* g, void* l) {
  __builtin_amdgcn_global_load_lds(
      (const __attribute__((address_space(1))) uint32_t*)g,
      (__attribute__((address_space(3))) uint32_t*)l, 16, 0, 0);
}

#define MFMA16(a,b,c) __builtin_amdgcn_mfma_f32_16x16x32_bf16((a),(b),(c),0,0,0)

// gate/softmax constants
#define C_NEG5L2E  (-7.213475204444817f)   // -5*log2(e)
#define C_L2E      (1.4426950408889634f)   // log2(e)
#define C_18L2E    (25.968510736001341f)   // 18*log2(e)

// ---------------- fused prep: quaternion weights + activation cvt + thresholds ----------------
// blocks [0,512): prep_w (8 elem/thread over 1M); [512,2560): cvt (8/thread over 4.19M); [2560,2576): thr.
__global__ __launch_bounds__(256) void prep_all(
    const float* __restrict__ wqr, const float* __restrict__ wqi,
    const float* __restrict__ wqj, const float* __restrict__ wqk,
    const float* __restrict__ wkr, const float* __restrict__ wki,
    const float* __restrict__ wkj, const float* __restrict__ wkk,
    const float* __restrict__ wv,  const float* __restrict__ wo,
    unsigned short* __restrict__ Wq, unsigned short* __restrict__ Wk,
    unsigned short* __restrict__ Wv, unsigned short* __restrict__ Wo,
    const float* __restrict__ query, const float* __restrict__ key_in,
    const float* __restrict__ value,
    unsigned short* __restrict__ qcv, unsigned short* __restrict__ kcv,
    unsigned short* __restrict__ vcv,
    const float* __restrict__ density, const float* __restrict__ dm1w,
    const float* __restrict__ dm1b, const float* __restrict__ dm2w,
    const float* __restrict__ dm2b, const float* __restrict__ thr_s,
    const int* __restrict__ mask, float2* __restrict__ klim,
    int* __restrict__ amask)
{
  const int bid = blockIdx.x;
  if (bid < 512) {
    const int idx = (bid * 256 + threadIdx.x) * 8;      // 8 consecutive elems, same row/block
    const int o = idx >> 10, i = idx & 1023;
    const int br = o >> 8, bc = i >> 8;
    const int ro = o & 255, ci = i & 255;
    const int comp[4][4] = {{0,1,2,3},{1,0,3,2},{2,3,0,1},{3,2,1,0}};
    const float sgn[4][4] = {{1.f,-1.f,-1.f,-1.f},{1.f,1.f,-1.f,1.f},{1.f,1.f,1.f,-1.f},{1.f,-1.f,1.f,1.f}};
    const float* pq[4] = {wqr, wqi, wqj, wqk};
    const float* pk[4] = {wkr, wki, wkj, wkk};
    const int c_ = comp[br][bc];
    const float s_ = sgn[br][bc];
    const float* qsrc = pq[c_] + ro * 256 + ci;
    const float* ksrc = pk[c_] + ro * 256 + ci;
    {
      const float4 f0 = *(const float4*)qsrc;
      const float4 f1 = *(const float4*)(qsrc + 4);
      union { unsigned short us[8]; u32x4 v; } t;
      t.us[0]=f2bf(s_*f0.x); t.us[1]=f2bf(s_*f0.y); t.us[2]=f2bf(s_*f0.z); t.us[3]=f2bf(s_*f0.w);
      t.us[4]=f2bf(s_*f1.x); t.us[5]=f2bf(s_*f1.y); t.us[6]=f2bf(s_*f1.z); t.us[7]=f2bf(s_*f1.w);
      *(u32x4*)(Wq + idx) = t.v;
    }
    {
      const float4 f0 = *(const float4*)ksrc;
      const float4 f1 = *(const float4*)(ksrc + 4);
      union { unsigned short us[8]; u32x4 v; } t;
      t.us[0]=f2bf(s_*f0.x); t.us[1]=f2bf(s_*f0.y); t.us[2]=f2bf(s_*f0.z); t.us[3]=f2bf(s_*f0.w);
      t.us[4]=f2bf(s_*f1.x); t.us[5]=f2bf(s_*f1.y); t.us[6]=f2bf(s_*f1.z); t.us[7]=f2bf(s_*f1.w);
      *(u32x4*)(Wk + idx) = t.v;
    }
    {
      const float4 f0 = *(const float4*)(wv + idx);
      const float4 f1 = *(const float4*)(wv + idx + 4);
      union { unsigned short us[8]; u32x4 v; } t;
      t.us[0]=f2bf(f0.x); t.us[1]=f2bf(f0.y); t.us[2]=f2bf(f0.z); t.us[3]=f2bf(f0.w);
      t.us[4]=f2bf(f1.x); t.us[5]=f2bf(f1.y); t.us[6]=f2bf(f1.z); t.us[7]=f2bf(f1.w);
      *(u32x4*)(Wv + idx) = t.v;
    }
    {
      const float4 f0 = *(const float4*)(wo + idx);
      const float4 f1 = *(const float4*)(wo + idx + 4);
      union { unsigned short us[8]; u32x4 v; } t;
      t.us[0]=f2bf(f0.x); t.us[1]=f2bf(f0.y); t.us[2]=f2bf(f0.z); t.us[3]=f2bf(f0.w);
      t.us[4]=f2bf(f1.x); t.us[5]=f2bf(f1.y); t.us[6]=f2bf(f1.z); t.us[7]=f2bf(f1.w);
      *(u32x4*)(Wo + idx) = t.v;
    }
  } else if (bid < 2560) {
    const int i8 = ((bid - 512) * 256 + threadIdx.x) * 8;
    {
      const float4 f0 = *(const float4*)(query + i8);
      const float4 f1 = *(const float4*)(query + i8 + 4);
      union { unsigned short us[8]; u32x4 v; } t;
      t.us[0]=f2bf(f0.x); t.us[1]=f2bf(f0.y); t.us[2]=f2bf(f0.z); t.us[3]=f2bf(f0.w);
      t.us[4]=f2bf(f1.x); t.us[5]=f2bf(f1.y); t.us[6]=f2bf(f1.z); t.us[7]=f2bf(f1.w);
      *(u32x4*)(qcv + i8) = t.v;
    }
    {
      const float4 f0 = *(const float4*)(key_in + i8);
      const float4 f1 = *(const float4*)(key_in + i8 + 4);
      union { unsigned short us[8]; u32x4 v; } t;
      t.us[0]=f2bf(f0.x); t.us[1]=f2bf(f0.y); t.us[2]=f2bf(f0.z); t.us[3]=f2bf(f0.w);
      t.us[4]=f2bf(f1.x); t.us[5]=f2bf(f1.y); t.us[6]=f2bf(f1.z); t.us[7]=f2bf(f1.w);
      *(u32x4*)(kcv + i8) = t.v;
    }
    {
      const float4 f0 = *(const float4*)(value + i8);
      const float4 f1 = *(const float4*)(value + i8 + 4);
      union { unsigned short us[8]; u32x4 v; } t;
      t.us[0]=f2bf(f0.x); t.us[1]=f2bf(f0.y); t.us[2]=f2bf(f0.z); t.us[3]=f2bf(f0.w);
      t.us[4]=f2bf(f1.x); t.us[5]=f2bf(f1.y); t.us[6]=f2bf(f1.z); t.us[7]=f2bf(f1.w);
      *(u32x4*)(vcv + i8) = t.v;
    }
  } else {
    const int i = (bid - 2560) * 256 + threadIdx.x;  // over B*S = 4096
    if (i >= BB * SS) return;
    const float x0 = density[i*3+0], x1 = density[i*3+1], x2 = density[i*3+2];
    const float base = log1pf(expf(thr_s[0]));     // softplus
    float acc = dm2b[0];
    #pragma unroll
    for (int j = 0; j < 16; ++j) {
      const float hj = dm1w[j*3+0]*x0 + dm1w[j*3+1]*x1 + dm1w[j*3+2]*x2 + dm1b[j];
      const float ge = 0.5f * hj * (1.0f + erff(hj * 0.70710678118654752f)); // exact gelu
      acc += dm2w[j] * ge;
    }
    const float thr = base + 0.1f * acc;
    const int mk = mask[i];
    klim[i] = make_float2(thr * (-C_NEG5L2E),          // +5*log2e*thr (exp2 arg offset)
                          mk ? 1e30f : -30.0f);        // mask limit for min
    const unsigned long long any = __ballot(mk == 0);
    if ((threadIdx.x & 63) == 0 && any)
      atomicOr(&amask[i >> 11], 1);                    // per-batch "has masked rows" flag
  }
}

// ---------------- GEMM: C(M=4096,N=1024) = A(M,K=1024) @ W(N,K)^T + bias ----------------
struct GemmArgs {
  const unsigned short* A[3];
  const unsigned short* W[3];
  const float* bias[3];
  void* out[3];
  float scale[3];
  int omode[3];
};

template<int DB>
__global__ __launch_bounds__(256) void gemm_bt(GemmArgs args)
{
  __shared__ __align__(16) unsigned short lA[DB + 1][128*64];
  __shared__ __align__(16) unsigned short lB[DB + 1][128*64];
  const int z = blockIdx.y;
  const int tid = threadIdx.x;
  const int wid = tid >> 6, lane = tid & 63;
  const int l15 = lane & 15, l4 = lane >> 4;
  const int bm = blockIdx.x & 31, bn = blockIdx.x >> 5;   // XCD-aware decode
  const int row0 = bm * 128, col0 = bn * 128;
  const int wm = (wid >> 1) * 64, wn = (wid & 1) * 64;

  const unsigned short* gA[4];
  const unsigned short* gB[4];
  #pragma unroll
  for (int i = 0; i < 4; ++i) {
    const int c = (wid * 4 + i) * 64 + lane;
    const int r = c >> 3, jx = c & 7, j = jx ^ (r & 7);
    gA[i] = args.A[z] + (row0 + r) * 1024 + j * 8;
    gB[i] = args.W[z] + (col0 + r) * 1024 + j * 8;
  }

  f32x4 acc[4][4];
  #pragma unroll
  for (int i = 0; i < 4; ++i)
    #pragma unroll
    for (int j = 0; j < 4; ++j) acc[i][j] = (f32x4){0.f,0.f,0.f,0.f};

  #pragma unroll
  for (int i = 0; i < 4; ++i) {
    gl16(gA[i], &lA[0][(wid * 4 + i) * 512]);
    gl16(gB[i], &lB[0][(wid * 4 + i) * 512]);
  }
  if (DB) __syncthreads();

  for (int kt = 0; kt < 16; ++kt) {
    const int cb = DB ? (kt & 1) : 0;
    if (DB) {
      if (kt < 15) {
        const int nb = cb ^ 1, k0 = (kt + 1) * 64;
        #pragma unroll
        for (int i = 0; i < 4; ++i) {
          gl16(gA[i] + k0, &lA[nb][(wid * 4 + i) * 512]);
          gl16(gB[i] + k0, &lB[nb][(wid * 4 + i) * 512]);
        }
      }
    } else {
      if (kt > 0) {
        const int k0 = kt * 64;
        #pragma unroll
        for (int i = 0; i < 4; ++i) {
          gl16(gA[i] + k0, &lA[0][(wid * 4 + i) * 512]);
          gl16(gB[i] + k0, &lB[0][(wid * 4 + i) * 512]);
        }
      }
      __syncthreads();
    }
    #pragma unroll
    for (int kk = 0; kk < 2; ++kk) {
      const int kl = kk * 32 + l4 * 8;
      bf16x8 af[4], bfb[4];
      #pragma unroll
      for (int mi = 0; mi < 4; ++mi) {
        const int r = wm + mi * 16 + l15;
        af[mi] = ldsv8(&lA[cb][r * 64 + (kl ^ ((r & 7) << 3))]);
      }
      #pragma unroll
      for (int nj = 0; nj < 4; ++nj) {
        const int r = wn + nj * 16 + l15;
        bfb[nj] = ldsv8(&lB[cb][r * 64 + (kl ^ ((r & 7) << 3))]);
      }
      #pragma unroll
      for (int mi = 0; mi < 4; ++mi)
        #pragma unroll
        for (int nj = 0; nj < 4; ++nj)
          acc[mi][nj] = MFMA16(af[mi], bfb[nj], acc[mi][nj]);
    }
    __syncthreads();
  }

  const int om = args.omode[z];
  const float sc = args.scale[z];
  void* Cptr = args.out[z];
  #pragma unroll
  for (int nj = 0; nj < 4; ++nj) {
    const int c = col0 + wn + nj * 16 + l15;
    const float bv_ = args.bias[z][c];
    #pragma unroll
    for (int mi = 0; mi < 4; ++mi) {
      const int rb = row0 + wm + mi * 16 + l4 * 4;
      #pragma unroll
      for (int e = 0; e < 4; ++e) {
        const float val = (acc[mi][nj][e] + bv_) * sc;
        const int r = rb + e;
        if (om == 0) {
          ((unsigned short*)Cptr)[r * 1024 + c] = f2bf(val);
        } else if (om == 2) {
          ((float*)Cptr)[r * 1024 + c] = val;
        } else {
          const int h = c >> 6, d = c & 63, b = r >> 11, s = r & 2047;
          ((unsigned short*)Cptr)[((h * BB + b) * HD + d) * SS + s] = f2bf(val);
        }
      }
    }
  }
}

// ---------------- flash attention with spike gate: split-K wave pairs ----------------
// R8 structure + global_load_lds staging (pre-swizzled source, linear LDS dest) +
// per-batch mask fast path + unroll-2. Fixed-max softmax; parity partials merged at end.
__global__ __launch_bounds__(512) void attn_kernel(
    const unsigned short* __restrict__ qg, const unsigned short* __restrict__ kg,
    const unsigned short* __restrict__ vT, const float2* __restrict__ klim,
    const int* __restrict__ mask, const int* __restrict__ amask,
    unsigned short* __restrict__ outg)
{
  __shared__ __align__(16) unsigned short smem[20480];   // 40 KB
  unsigned char* sb = (unsigned char*)smem;
  // byte map: K pair-buffers [0,16384) (cur*8192), V [16384,32768), P [32768,40960)
  unsigned short* lK = smem;            // shorts view for reads
  unsigned short* lV = smem + 8192;
  unsigned short* lP = smem + 16384;

  const int tid = threadIdx.x;
  const int wid = tid >> 6, lane = tid & 63;
  const int l15 = lane & 15, l4 = lane >> 4;
  const int rg = wid >> 1, par = wid & 1;
  const int hb = blockIdx.x & 31, qb = blockIdx.x >> 5;  // XCD: same (h,b) -> same XCD
  const int h = hb >> 1, b = hb & 1;
  const int qr0 = qb * 64 + rg * 16;

  const unsigned short* kbase = kg + (b * SS) * DM + h * HD;
  const unsigned short* vbase = vT + ((h * BB + b) * HD) * SS;
  const float2* klimb = klim + b * SS;
  const int clean = (amask[b] == 0);

  // --- global_load_lds source mapping (inverse of the XOR-swizzled LDS layout) ---
  // K: wave w covers LDS bytes [w*1024,(w+1)*1024) of the K pair-buffer:
  //    parity p=w>>2, row rho=((w&3)<<3)|(l>>3), slot=l&7 holds chunk j=slot^((rho>>1)&7)
  const int kp   = wid >> 2;
  const int krho = ((wid & 3) << 3) | (lane >> 3);
  const int kj   = (lane & 7) ^ ((krho >> 1) & 7);
  const unsigned short* ksrc = kbase + (kp * 32 + krho) * DM + kj * 8;
  // V: parity q=w>>2, d=((w&3)<<4)|(l>>2), slot=l&3 holds chunk c=slot^(d&3)
  const int vq   = wid >> 2;
  const int vd   = ((wid & 3) << 4) | (lane >> 2);
  const int vc   = (lane & 3) ^ (vd & 3);
  const unsigned short* vsrc = vbase + (size_t)vd * SS + vq * 32 + vc * 8;
  unsigned char* kdw = sb + wid * 1024;            // + cur*8192
  unsigned char* vdw = sb + 16384 + wid * 1024;    // + cur*8192

  // Q fragments (A-frag: row=lane%16, k=(lane>>4)*8); Q pre-scaled by 0.25
  bf16x8 aq[2];
  {
    const unsigned short* qs = qg + (b * SS + qr0 + l15) * DM + h * HD + l4 * 8;
    aq[0] = __builtin_bit_cast(bf16x8, *(const u32x4*)qs);
    aq[1] = __builtin_bit_cast(bf16x8, *(const u32x4*)(qs + 32));
  }
  float limq[4];
  if (!clean) {
    #pragma unroll
    for (int e = 0; e < 4; ++e)
      limq[e] = mask[b * SS + qr0 + l4 * 4 + e] ? 1e30f : -30.0f;
  }

  float lrun[4] = {0.f, 0.f, 0.f, 0.f};
  f32x4 o[4];
  #pragma unroll
  for (int d = 0; d < 4; ++d) o[d] = (f32x4){0.f,0.f,0.f,0.f};

  unsigned short* lPw = lP + wid * 512;

  // prologue: stage pair 0 via async global->LDS
  gl16(ksrc, kdw);
  gl16(vsrc, vdw);
  __syncthreads();

  #pragma unroll 2
  for (int pr = 0; pr < 32; ++pr) {
    const int cur = pr & 1;
    const unsigned short* lKt = lK + cur * 4096 + par * 2048;
    const unsigned short* lVt = lV + cur * 4096 + par * 2048;
    const int n0 = pr * 64 + par * 32;

    // issue async staging of the next pair into the other buffer
    if (pr < 31) {
      const int nxt = cur ^ 1;
      gl16(ksrc + (size_t)(pr + 1) * 64 * DM, kdw + nxt * 8192);
      gl16(vsrc + (pr + 1) * 64,              vdw + nxt * 8192);
    }

    const float4 klA = *(const float4*)(klimb + n0 + 2 * l15);   // keys 2l15, 2l15+1

    // S = Q @ K^T : key = 2*l15 + cf
    f32x4 sv[2];
    __builtin_amdgcn_s_setprio(1);
    #pragma unroll
    for (int cf = 0; cf < 2; ++cf) {
      f32x4 a = (f32x4){0.f,0.f,0.f,0.f};
      const int r = 2 * l15 + cf;
      #pragma unroll
      for (int kk = 0; kk < 2; ++kk)
        a = MFMA16(aq[kk], ldsv8(&lKt[r * 64 + ((kk * 32 + l4 * 8) ^ ((l15 & 7) << 3))]), a);
      sv[cf] = a;
    }
    __builtin_amdgcn_s_setprio(0);

    // spike gate + mask + fixed-max softmax numerator
    float pvv[2][4];
    if (clean) {
      #pragma unroll
      for (int cf = 0; cf < 2; ++cf) {
        const float kth = cf ? klA.z : klA.x;
        #pragma unroll
        for (int e = 0; e < 4; ++e) {
          float s = fminf(fmaxf(sv[cf][e], -6.f), 6.f);
          const float t = __builtin_amdgcn_exp2f(fmaf(s, C_NEG5L2E, kth));
          const float g = __builtin_amdgcn_rcpf(1.f + t);
          const float md = fmaf(s + s, g, s);                   // s*(1+2g) in [-18,18]
          const float p = __builtin_amdgcn_exp2f(fmaf(md, C_L2E, -C_18L2E)); // exp(md-18)
          pvv[cf][e] = p;
          lrun[e] += p;
        }
      }
    } else {
      #pragma unroll
      for (int cf = 0; cf < 2; ++cf) {
        const float kth = cf ? klA.z : klA.x;
        const float klm = cf ? klA.w : klA.y;
        #pragma unroll
        for (int e = 0; e < 4; ++e) {
          float s = fminf(fmaxf(sv[cf][e], -6.f), 6.f);
          const float t = __builtin_amdgcn_exp2f(fmaf(s, C_NEG5L2E, kth));
          const float g = __builtin_amdgcn_rcpf(1.f + t);
          float md = fmaf(s + s, g, s);
          md = fminf(md, fminf(klm, limq[e]));                  // mask -> -30
          const float p = __builtin_amdgcn_exp2f(fmaf(md, C_L2E, -C_18L2E));
          pvv[cf][e] = p;
          lrun[e] += p;
        }
      }
    }

    // P -> per-wave LDS: packed pair writes (keys 2l15, 2l15+1)
    #pragma unroll
    for (int e = 0; e < 4; ++e) {
      const int rr = l4 * 4 + e;
      union { unsigned short us[2]; unsigned int u; } pk2;
      pk2.us[0] = f2bf(pvv[0][e]);
      pk2.us[1] = f2bf(pvv[1][e]);
      *(unsigned int*)&lPw[rr * 32 + ((2 * l15) ^ ((rr & 3) << 3))] = pk2.u;
    }
    asm volatile("s_waitcnt lgkmcnt(0)" ::: "memory");
    __builtin_amdgcn_sched_barrier(0);

    const bf16x8 pa = ldsv8(&lPw[l15 * 32 + ((l4 * 8) ^ ((l15 & 3) << 3))]);

    __builtin_amdgcn_s_setprio(1);
    #pragma unroll
    for (int df = 0; df < 4; ++df) {
      const int d = df * 16 + l15;
      o[df] = MFMA16(pa, ldsv8(&lVt[d * 32 + ((l4 * 8) ^ ((d & 3) << 3))]), o[df]);
    }
    __builtin_amdgcn_s_setprio(0);

    __syncthreads();   // drains vmcnt -> next pair's LDS data is ready
  }

  // merge parity partials via LDS (smem reuse), normalize, store
  __syncthreads();
  float* xch = (float*)smem;
  float* slot = xch + rg * 1280;
  if (par) {
    #pragma unroll
    for (int df = 0; df < 4; ++df)
      *(f32x4*)&slot[(df * 64 + lane) * 4] = o[df];
    f32x4 lr;
    lr[0] = lrun[0]; lr[1] = lrun[1]; lr[2] = lrun[2]; lr[3] = lrun[3];
    *(f32x4*)&slot[1024 + lane * 4] = lr;
  }
  __syncthreads();
  if (!par) {
    #pragma unroll
    for (int df = 0; df < 4; ++df) {
      const f32x4 t = *(const f32x4*)&slot[(df * 64 + lane) * 4];
      o[df][0] += t[0]; o[df][1] += t[1]; o[df][2] += t[2]; o[df][3] += t[3];
    }
    const f32x4 lr = *(const f32x4*)&slot[1024 + lane * 4];
    #pragma unroll
    for (int e = 0; e < 4; ++e) {
      float ls = lrun[e] + lr[e];
      ls += __shfl_xor(ls, 1);
      ls += __shfl_xor(ls, 2);
      ls += __shfl_xor(ls, 4);
      ls += __shfl_xor(ls, 8);
      const float rl = __builtin_amdgcn_rcpf(ls);
      const int r = qr0 + l4 * 4 + e;
      #pragma unroll
      for (int df = 0; df < 4; ++df) {
        outg[(b * SS + r) * DM + h * HD + df * 16 + l15] = f2bf(o[df][e] * rl);
      }
    }
  }
}

// ---------------- launcher ----------------
extern "C" void kernel_launch(void* const* d_in, const int* in_sizes, int n_in,
                              void* d_out, int out_size, void* d_ws, size_t ws_size,
                              hipStream_t stream)
{
  const float* query   = (const float*)d_in[0];
  const float* key_in  = (const float*)d_in[1];
  const float* value   = (const float*)d_in[2];
  const int*   mask    = (const int*)d_in[3];
  const float* density = (const float*)d_in[4];
  const float* wq_r = (const float*)d_in[5];
  const float* wq_i = (const float*)d_in[6];
  const float* wq_j = (const float*)d_in[7];
  const float* wq_k = (const float*)d_in[8];
  const float* bq   = (const float*)d_in[9];
  const float* wk_r = (const float*)d_in[10];
  const float* wk_i = (const float*)d_in[11];
  const float* wk_j = (const float*)d_in[12];
  const float* wk_k = (const float*)d_in[13];
  const float* bk   = (const float*)d_in[14];
  const float* wv   = (const float*)d_in[15];
  const float* bv   = (const float*)d_in[16];
  const float* wo   = (const float*)d_in[17];
  const float* bo   = (const float*)d_in[18];
  const float* thrs = (const float*)d_in[19];
  const float* dm1w = (const float*)d_in[20];
  const float* dm1b = (const float*)d_in[21];
  const float* dm2w = (const float*)d_in[22];
  const float* dm2b = (const float*)d_in[23];

  char* ws = (char*)d_ws;
  unsigned short* Wq  = (unsigned short*)(ws + ((size_t)0 << 20));
  unsigned short* Wk  = (unsigned short*)(ws + ((size_t)2 << 20));
  unsigned short* Wv  = (unsigned short*)(ws + ((size_t)4 << 20));
  unsigned short* Wo  = (unsigned short*)(ws + ((size_t)6 << 20));
  unsigned short* qbf = (unsigned short*)(ws + ((size_t)8 << 20));
  unsigned short* kbf = (unsigned short*)(ws + ((size_t)16 << 20));
  unsigned short* vT  = (unsigned short*)(ws + ((size_t)24 << 20));
  unsigned short* att = (unsigned short*)(ws + ((size_t)32 << 20));
  float2* klim        = (float2*)(ws + ((size_t)40 << 20));
  int* amask          = (int*)(ws + ((size_t)40 << 20) + 65536);

  unsigned short* qcv = (unsigned short*)d_out;
  unsigned short* kcv = (unsigned short*)d_out + (size_t)MTOT * DM;
  unsigned short* vcv = att;

  hipMemsetAsync(amask, 0, 2 * sizeof(int), stream);
  prep_all<<<2576, 256, 0, stream>>>(
      wq_r, wq_i, wq_j, wq_k, wk_r, wk_i, wk_j, wk_k, wv, wo,
      Wq, Wk, Wv, Wo,
      query, key_in, value, qcv, kcv, vcv,
      density, dm1w, dm1b, dm2w, dm2b, thrs, mask, klim, amask);

  GemmArgs qkv;
  qkv.A[0] = qcv; qkv.W[0] = Wq; qkv.bias[0] = bq; qkv.out[0] = qbf; qkv.scale[0] = 0.25f; qkv.omode[0] = 0;
  qkv.A[1] = kcv; qkv.W[1] = Wk; qkv.bias[1] = bk; qkv.out[1] = kbf; qkv.scale[1] = 1.0f;  qkv.omode[1] = 0;
  qkv.A[2] = vcv; qkv.W[2] = Wv; qkv.bias[2] = bv; qkv.out[2] = vT;  qkv.scale[2] = 1.0f;  qkv.omode[2] = 1;
  gemm_bt<0><<<dim3(256, 3), 256, 0, stream>>>(qkv);

  attn_kernel<<<1024, 512, 0, stream>>>(qbf, kbf, vT, klim, mask, amask, att);

  GemmArgs og;
  og.A[0] = att; og.W[0] = Wo; og.bias[0] = bo; og.out[0] = d_out; og.scale[0] = 1.0f; og.omode[0] = 2;
  og.A[1] = att; og.W[1] = Wo; og.bias[1] = bo; og.out[1] = d_out; og.scale[1] = 1.0f; og.omode[1] = 2;
  og.A[2] = att; og.W[2] = Wo; og.bias[2] = bo; og.out[2] = d_out; og.scale[2] = 1.0f; og.omode[2] = 2;
  gemm_bt<1><<<dim3(256, 1), 256, 0, stream>>>(og);
}

// Round 10
// 180.538 us; speedup vs baseline: 1.0251x; 1.0251x over previous
//
#include <hip/hip_runtime.h>
#include <stdint.h>
#include <math.h>

#define BB 2
#define SS 2048
#define DM 1024
#define NH 16
#define HD 64
#define MTOT (BB*SS)

typedef __bf16 bf16x8 __attribute__((ext_vector_type(8)));
typedef float  f32x4  __attribute__((ext_vector_type(4)));
typedef float  f32x2  __attribute__((ext_vector_type(2)));
typedef uint32_t u32x4 __attribute__((ext_vector_type(4)));

__device__ __forceinline__ unsigned short f2bf(float f) {
  __bf16 h = (__bf16)f;                 // RNE; compiler packs to v_cvt_pk_bf16_f32
  return __builtin_bit_cast(unsigned short, h);
}

__device__ __forceinline__ bf16x8 ldsv8(const unsigned short* p) {
  return __builtin_bit_cast(bf16x8, *(const u32x4*)p);
}

__device__ __forceinline__ void gl16(const void* g, void* l) {
  __builtin_amdgcn_global_load_lds(
      (const __attribute__((address_space(1))) uint32_t*)g,
      (__attribute__((address_space(3))) uint32_t*)l, 16, 0, 0);
}

#define MFMA16(a,b,c) __builtin_amdgcn_mfma_f32_16x16x32_bf16((a),(b),(c),0,0,0)

// gate/softmax constants
#define C_NEG5L2E  (-7.213475204444817f)   // -5*log2(e)
#define C_L2E      (1.4426950408889634f)   // log2(e)
#define C_18L2E    (25.968510736001341f)   // 18*log2(e)

// packed (v_pk_*) gate evaluation for an e-pair: returns p = exp(mod-18), accumulates into lr
__device__ __forceinline__ f32x2 gate_pk(f32x2 s2, float kth, f32x2& lr) {
  s2 = __builtin_elementwise_min(__builtin_elementwise_max(s2, (f32x2){-6.f,-6.f}), (f32x2){6.f,6.f});
  const f32x2 targ = __builtin_elementwise_fma(s2, (f32x2){C_NEG5L2E, C_NEG5L2E}, (f32x2){kth, kth});
  f32x2 t;
  t.x = __builtin_amdgcn_exp2f(targ.x);
  t.y = __builtin_amdgcn_exp2f(targ.y);
  const f32x2 den = t + (f32x2){1.f, 1.f};
  f32x2 g;
  g.x = __builtin_amdgcn_rcpf(den.x);
  g.y = __builtin_amdgcn_rcpf(den.y);
  const f32x2 md = __builtin_elementwise_fma(s2 + s2, g, s2);       // s*(1+2g)
  const f32x2 pa = __builtin_elementwise_fma(md, (f32x2){C_L2E, C_L2E}, (f32x2){-C_18L2E, -C_18L2E});
  f32x2 p;
  p.x = __builtin_amdgcn_exp2f(pa.x);
  p.y = __builtin_amdgcn_exp2f(pa.y);
  lr += p;
  return p;
}

// ---------------- fused prep: quaternion weights + activation cvt + thresholds ----------------
// blocks [0,512): prep_w (8 elem/thread over 1M); [512,2560): cvt (8/thread over 4.19M); [2560,2576): thr.
__global__ __launch_bounds__(256) void prep_all(
    const float* __restrict__ wqr, const float* __restrict__ wqi,
    const float* __restrict__ wqj, const float* __restrict__ wqk,
    const float* __restrict__ wkr, const float* __restrict__ wki,
    const float* __restrict__ wkj, const float* __restrict__ wkk,
    const float* __restrict__ wv,  const float* __restrict__ wo,
    unsigned short* __restrict__ Wq, unsigned short* __restrict__ Wk,
    unsigned short* __restrict__ Wv, unsigned short* __restrict__ Wo,
    const float* __restrict__ query, const float* __restrict__ key_in,
    const float* __restrict__ value,
    unsigned short* __restrict__ qcv, unsigned short* __restrict__ kcv,
    unsigned short* __restrict__ vcv,
    const float* __restrict__ density, const float* __restrict__ dm1w,
    const float* __restrict__ dm1b, const float* __restrict__ dm2w,
    const float* __restrict__ dm2b, const float* __restrict__ thr_s,
    const int* __restrict__ mask, float2* __restrict__ klim,
    int* __restrict__ amask)
{
  const int bid = blockIdx.x;
  if (bid < 512) {
    const int idx = (bid * 256 + threadIdx.x) * 8;      // 8 consecutive elems, same row/block
    const int o = idx >> 10, i = idx & 1023;
    const int br = o >> 8, bc = i >> 8;
    const int ro = o & 255, ci = i & 255;
    const int comp[4][4] = {{0,1,2,3},{1,0,3,2},{2,3,0,1},{3,2,1,0}};
    const float sgn[4][4] = {{1.f,-1.f,-1.f,-1.f},{1.f,1.f,-1.f,1.f},{1.f,1.f,1.f,-1.f},{1.f,-1.f,1.f,1.f}};
    const float* pq[4] = {wqr, wqi, wqj, wqk};
    const float* pk[4] = {wkr, wki, wkj, wkk};
    const int c_ = comp[br][bc];
    const float s_ = sgn[br][bc];
    const float* qsrc = pq[c_] + ro * 256 + ci;
    const float* ksrc = pk[c_] + ro * 256 + ci;
    {
      const float4 f0 = *(const float4*)qsrc;
      const float4 f1 = *(const float4*)(qsrc + 4);
      union { unsigned short us[8]; u32x4 v; } t;
      t.us[0]=f2bf(s_*f0.x); t.us[1]=f2bf(s_*f0.y); t.us[2]=f2bf(s_*f0.z); t.us[3]=f2bf(s_*f0.w);
      t.us[4]=f2bf(s_*f1.x); t.us[5]=f2bf(s_*f1.y); t.us[6]=f2bf(s_*f1.z); t.us[7]=f2bf(s_*f1.w);
      *(u32x4*)(Wq + idx) = t.v;
    }
    {
      const float4 f0 = *(const float4*)ksrc;
      const float4 f1 = *(const float4*)(ksrc + 4);
      union { unsigned short us[8]; u32x4 v; } t;
      t.us[0]=f2bf(s_*f0.x); t.us[1]=f2bf(s_*f0.y); t.us[2]=f2bf(s_*f0.z); t.us[3]=f2bf(s_*f0.w);
      t.us[4]=f2bf(s_*f1.x); t.us[5]=f2bf(s_*f1.y); t.us[6]=f2bf(s_*f1.z); t.us[7]=f2bf(s_*f1.w);
      *(u32x4*)(Wk + idx) = t.v;
    }
    {
      const float4 f0 = *(const float4*)(wv + idx);
      const float4 f1 = *(const float4*)(wv + idx + 4);
      union { unsigned short us[8]; u32x4 v; } t;
      t.us[0]=f2bf(f0.x); t.us[1]=f2bf(f0.y); t.us[2]=f2bf(f0.z); t.us[3]=f2bf(f0.w);
      t.us[4]=f2bf(f1.x); t.us[5]=f2bf(f1.y); t.us[6]=f2bf(f1.z); t.us[7]=f2bf(f1.w);
      *(u32x4*)(Wv + idx) = t.v;
    }
    {
      const float4 f0 = *(const float4*)(wo + idx);
      const float4 f1 = *(const float4*)(wo + idx + 4);
      union { unsigned short us[8]; u32x4 v; } t;
      t.us[0]=f2bf(f0.x); t.us[1]=f2bf(f0.y); t.us[2]=f2bf(f0.z); t.us[3]=f2bf(f0.w);
      t.us[4]=f2bf(f1.x); t.us[5]=f2bf(f1.y); t.us[6]=f2bf(f1.z); t.us[7]=f2bf(f1.w);
      *(u32x4*)(Wo + idx) = t.v;
    }
  } else if (bid < 2560) {
    const int i8 = ((bid - 512) * 256 + threadIdx.x) * 8;
    {
      const float4 f0 = *(const float4*)(query + i8);
      const float4 f1 = *(const float4*)(query + i8 + 4);
      union { unsigned short us[8]; u32x4 v; } t;
      t.us[0]=f2bf(f0.x); t.us[1]=f2bf(f0.y); t.us[2]=f2bf(f0.z); t.us[3]=f2bf(f0.w);
      t.us[4]=f2bf(f1.x); t.us[5]=f2bf(f1.y); t.us[6]=f2bf(f1.z); t.us[7]=f2bf(f1.w);
      *(u32x4*)(qcv + i8) = t.v;
    }
    {
      const float4 f0 = *(const float4*)(key_in + i8);
      const float4 f1 = *(const float4*)(key_in + i8 + 4);
      union { unsigned short us[8]; u32x4 v; } t;
      t.us[0]=f2bf(f0.x); t.us[1]=f2bf(f0.y); t.us[2]=f2bf(f0.z); t.us[3]=f2bf(f0.w);
      t.us[4]=f2bf(f1.x); t.us[5]=f2bf(f1.y); t.us[6]=f2bf(f1.z); t.us[7]=f2bf(f1.w);
      *(u32x4*)(kcv + i8) = t.v;
    }
    {
      const float4 f0 = *(const float4*)(value + i8);
      const float4 f1 = *(const float4*)(value + i8 + 4);
      union { unsigned short us[8]; u32x4 v; } t;
      t.us[0]=f2bf(f0.x); t.us[1]=f2bf(f0.y); t.us[2]=f2bf(f0.z); t.us[3]=f2bf(f0.w);
      t.us[4]=f2bf(f1.x); t.us[5]=f2bf(f1.y); t.us[6]=f2bf(f1.z); t.us[7]=f2bf(f1.w);
      *(u32x4*)(vcv + i8) = t.v;
    }
  } else {
    const int i = (bid - 2560) * 256 + threadIdx.x;  // over B*S = 4096
    if (i >= BB * SS) return;
    const float x0 = density[i*3+0], x1 = density[i*3+1], x2 = density[i*3+2];
    const float base = log1pf(expf(thr_s[0]));     // softplus
    float acc = dm2b[0];
    #pragma unroll
    for (int j = 0; j < 16; ++j) {
      const float hj = dm1w[j*3+0]*x0 + dm1w[j*3+1]*x1 + dm1w[j*3+2]*x2 + dm1b[j];
      const float ge = 0.5f * hj * (1.0f + erff(hj * 0.70710678118654752f)); // exact gelu
      acc += dm2w[j] * ge;
    }
    const float thr = base + 0.1f * acc;
    const int mk = mask[i];
    klim[i] = make_float2(thr * (-C_NEG5L2E),          // +5*log2e*thr (exp2 arg offset)
                          mk ? 1e30f : -30.0f);        // mask limit for min
    const unsigned long long any = __ballot(mk == 0);
    if ((threadIdx.x & 63) == 0 && any)
      atomicOr(&amask[i >> 11], 1);                    // per-batch "has masked rows" flag
  }
}

// ---------------- GEMM: C(M=4096,N=1024) = A(M,K=1024) @ W(N,K)^T + bias ----------------
struct GemmArgs {
  const unsigned short* A[3];
  const unsigned short* W[3];
  const float* bias[3];
  void* out[3];
  float scale[3];
  int omode[3];
};

template<int DB>
__global__ __launch_bounds__(256) void gemm_bt(GemmArgs args)
{
  __shared__ __align__(16) unsigned short lA[DB + 1][128*64];
  __shared__ __align__(16) unsigned short lB[DB + 1][128*64];
  const int z = blockIdx.y;
  const int tid = threadIdx.x;
  const int wid = tid >> 6, lane = tid & 63;
  const int l15 = lane & 15, l4 = lane >> 4;
  const int bm = blockIdx.x & 31, bn = blockIdx.x >> 5;   // XCD-aware decode
  const int row0 = bm * 128, col0 = bn * 128;
  const int wm = (wid >> 1) * 64, wn = (wid & 1) * 64;

  const unsigned short* gA[4];
  const unsigned short* gB[4];
  #pragma unroll
  for (int i = 0; i < 4; ++i) {
    const int c = (wid * 4 + i) * 64 + lane;
    const int r = c >> 3, jx = c & 7, j = jx ^ (r & 7);
    gA[i] = args.A[z] + (row0 + r) * 1024 + j * 8;
    gB[i] = args.W[z] + (col0 + r) * 1024 + j * 8;
  }

  f32x4 acc[4][4];
  #pragma unroll
  for (int i = 0; i < 4; ++i)
    #pragma unroll
    for (int j = 0; j < 4; ++j) acc[i][j] = (f32x4){0.f,0.f,0.f,0.f};

  #pragma unroll
  for (int i = 0; i < 4; ++i) {
    gl16(gA[i], &lA[0][(wid * 4 + i) * 512]);
    gl16(gB[i], &lB[0][(wid * 4 + i) * 512]);
  }
  if (DB) __syncthreads();

  for (int kt = 0; kt < 16; ++kt) {
    const int cb = DB ? (kt & 1) : 0;
    if (DB) {
      if (kt < 15) {
        const int nb = cb ^ 1, k0 = (kt + 1) * 64;
        #pragma unroll
        for (int i = 0; i < 4; ++i) {
          gl16(gA[i] + k0, &lA[nb][(wid * 4 + i) * 512]);
          gl16(gB[i] + k0, &lB[nb][(wid * 4 + i) * 512]);
        }
      }
    } else {
      if (kt > 0) {
        const int k0 = kt * 64;
        #pragma unroll
        for (int i = 0; i < 4; ++i) {
          gl16(gA[i] + k0, &lA[0][(wid * 4 + i) * 512]);
          gl16(gB[i] + k0, &lB[0][(wid * 4 + i) * 512]);
        }
      }
      __syncthreads();
    }
    #pragma unroll
    for (int kk = 0; kk < 2; ++kk) {
      const int kl = kk * 32 + l4 * 8;
      bf16x8 af[4], bfb[4];
      #pragma unroll
      for (int mi = 0; mi < 4; ++mi) {
        const int r = wm + mi * 16 + l15;
        af[mi] = ldsv8(&lA[cb][r * 64 + (kl ^ ((r & 7) << 3))]);
      }
      #pragma unroll
      for (int nj = 0; nj < 4; ++nj) {
        const int r = wn + nj * 16 + l15;
        bfb[nj] = ldsv8(&lB[cb][r * 64 + (kl ^ ((r & 7) << 3))]);
      }
      #pragma unroll
      for (int mi = 0; mi < 4; ++mi)
        #pragma unroll
        for (int nj = 0; nj < 4; ++nj)
          acc[mi][nj] = MFMA16(af[mi], bfb[nj], acc[mi][nj]);
    }
    __syncthreads();
  }

  const int om = args.omode[z];
  const float sc = args.scale[z];
  void* Cptr = args.out[z];
  #pragma unroll
  for (int nj = 0; nj < 4; ++nj) {
    const int c = col0 + wn + nj * 16 + l15;
    const float bv_ = args.bias[z][c];
    #pragma unroll
    for (int mi = 0; mi < 4; ++mi) {
      const int rb = row0 + wm + mi * 16 + l4 * 4;
      #pragma unroll
      for (int e = 0; e < 4; ++e) {
        const float val = (acc[mi][nj][e] + bv_) * sc;
        const int r = rb + e;
        if (om == 0) {
          ((unsigned short*)Cptr)[r * 1024 + c] = f2bf(val);
        } else if (om == 2) {
          ((float*)Cptr)[r * 1024 + c] = val;
        } else {
          const int h = c >> 6, d = c & 63, b = r >> 11, s = r & 2047;
          ((unsigned short*)Cptr)[((h * BB + b) * HD + d) * SS + s] = f2bf(val);
        }
      }
    }
  }
}

// ---------------- flash attention with spike gate: split-K wave pairs ----------------
// R9 structure (global_load_lds staging, mask fast path) + packed-f32 (v_pk_*) gate math.
__global__ __launch_bounds__(512) void attn_kernel(
    const unsigned short* __restrict__ qg, const unsigned short* __restrict__ kg,
    const unsigned short* __restrict__ vT, const float2* __restrict__ klim,
    const int* __restrict__ mask, const int* __restrict__ amask,
    unsigned short* __restrict__ outg)
{
  __shared__ __align__(16) unsigned short smem[20480];   // 40 KB
  unsigned char* sb = (unsigned char*)smem;
  unsigned short* lK = smem;
  unsigned short* lV = smem + 8192;
  unsigned short* lP = smem + 16384;

  const int tid = threadIdx.x;
  const int wid = tid >> 6, lane = tid & 63;
  const int l15 = lane & 15, l4 = lane >> 4;
  const int rg = wid >> 1, par = wid & 1;
  const int hb = blockIdx.x & 31, qb = blockIdx.x >> 5;  // XCD: same (h,b) -> same XCD
  const int h = hb >> 1, b = hb & 1;
  const int qr0 = qb * 64 + rg * 16;

  const unsigned short* kbase = kg + (b * SS) * DM + h * HD;
  const unsigned short* vbase = vT + ((h * BB + b) * HD) * SS;
  const float2* klimb = klim + b * SS;
  const int clean = (amask[b] == 0);

  // global_load_lds source mapping (inverse of the XOR-swizzled LDS layout)
  const int kp   = wid >> 2;
  const int krho = ((wid & 3) << 3) | (lane >> 3);
  const int kj   = (lane & 7) ^ ((krho >> 1) & 7);
  const unsigned short* ksrc = kbase + (kp * 32 + krho) * DM + kj * 8;
  const int vq   = wid >> 2;
  const int vd   = ((wid & 3) << 4) | (lane >> 2);
  const int vc   = (lane & 3) ^ (vd & 3);
  const unsigned short* vsrc = vbase + (size_t)vd * SS + vq * 32 + vc * 8;
  unsigned char* kdw = sb + wid * 1024;            // + cur*8192
  unsigned char* vdw = sb + 16384 + wid * 1024;    // + cur*8192

  // Q fragments (A-frag: row=lane%16, k=(lane>>4)*8); Q pre-scaled by 0.25
  bf16x8 aq[2];
  {
    const unsigned short* qs = qg + (b * SS + qr0 + l15) * DM + h * HD + l4 * 8;
    aq[0] = __builtin_bit_cast(bf16x8, *(const u32x4*)qs);
    aq[1] = __builtin_bit_cast(bf16x8, *(const u32x4*)(qs + 32));
  }
  float limq[4];
  if (!clean) {
    #pragma unroll
    for (int e = 0; e < 4; ++e)
      limq[e] = mask[b * SS + qr0 + l4 * 4 + e] ? 1e30f : -30.0f;
  }

  f32x2 lr01 = {0.f, 0.f}, lr23 = {0.f, 0.f};    // packed row-sum accumulators (e={0,1},{2,3})
  f32x4 o[4];
  #pragma unroll
  for (int d = 0; d < 4; ++d) o[d] = (f32x4){0.f,0.f,0.f,0.f};

  unsigned short* lPw = lP + wid * 512;

  // prologue: stage pair 0 via async global->LDS
  gl16(ksrc, kdw);
  gl16(vsrc, vdw);
  __syncthreads();

  #pragma unroll 2
  for (int pr = 0; pr < 32; ++pr) {
    const int cur = pr & 1;
    const unsigned short* lKt = lK + cur * 4096 + par * 2048;
    const unsigned short* lVt = lV + cur * 4096 + par * 2048;
    const int n0 = pr * 64 + par * 32;

    // issue async staging of the next pair into the other buffer
    if (pr < 31) {
      const int nxt = cur ^ 1;
      gl16(ksrc + (size_t)(pr + 1) * 64 * DM, kdw + nxt * 8192);
      gl16(vsrc + (pr + 1) * 64,              vdw + nxt * 8192);
    }

    const float4 klA = *(const float4*)(klimb + n0 + 2 * l15);   // keys 2l15, 2l15+1

    // S = Q @ K^T : key = 2*l15 + cf
    f32x4 sv[2];
    __builtin_amdgcn_s_setprio(1);
    #pragma unroll
    for (int cf = 0; cf < 2; ++cf) {
      f32x4 a = (f32x4){0.f,0.f,0.f,0.f};
      const int r = 2 * l15 + cf;
      #pragma unroll
      for (int kk = 0; kk < 2; ++kk)
        a = MFMA16(aq[kk], ldsv8(&lKt[r * 64 + ((kk * 32 + l4 * 8) ^ ((l15 & 7) << 3))]), a);
      sv[cf] = a;
    }
    __builtin_amdgcn_s_setprio(0);

    // spike gate + mask + fixed-max softmax numerator
    f32x2 p01[2], p23[2];                         // [cf] x e-pairs
    if (clean) {
      #pragma unroll
      for (int cf = 0; cf < 2; ++cf) {
        const float kth = cf ? klA.z : klA.x;
        p01[cf] = gate_pk((f32x2){sv[cf][0], sv[cf][1]}, kth, lr01);
        p23[cf] = gate_pk((f32x2){sv[cf][2], sv[cf][3]}, kth, lr23);
      }
    } else {
      #pragma unroll
      for (int cf = 0; cf < 2; ++cf) {
        const float kth = cf ? klA.z : klA.x;
        const float klm = cf ? klA.w : klA.y;
        float pe[4];
        #pragma unroll
        for (int e = 0; e < 4; ++e) {
          float s = fminf(fmaxf(sv[cf][e], -6.f), 6.f);
          const float t = __builtin_amdgcn_exp2f(fmaf(s, C_NEG5L2E, kth));
          const float g = __builtin_amdgcn_rcpf(1.f + t);
          float md = fmaf(s + s, g, s);
          md = fminf(md, fminf(klm, limq[e]));                  // mask -> -30
          pe[e] = __builtin_amdgcn_exp2f(fmaf(md, C_L2E, -C_18L2E));
        }
        p01[cf] = (f32x2){pe[0], pe[1]};
        p23[cf] = (f32x2){pe[2], pe[3]};
        lr01 += p01[cf];
        lr23 += p23[cf];
      }
    }

    // P -> per-wave LDS: packed pair writes (keys 2l15, 2l15+1)
    #pragma unroll
    for (int e = 0; e < 4; ++e) {
      const int rr = l4 * 4 + e;
      const float pa_ = (e < 2) ? p01[0][e] : p23[0][e - 2];
      const float pb_ = (e < 2) ? p01[1][e] : p23[1][e - 2];
      union { unsigned short us[2]; unsigned int u; } pk2;
      pk2.us[0] = f2bf(pa_);
      pk2.us[1] = f2bf(pb_);
      *(unsigned int*)&lPw[rr * 32 + ((2 * l15) ^ ((rr & 3) << 3))] = pk2.u;
    }
    asm volatile("s_waitcnt lgkmcnt(0)" ::: "memory");
    __builtin_amdgcn_sched_barrier(0);

    const bf16x8 pa = ldsv8(&lPw[l15 * 32 + ((l4 * 8) ^ ((l15 & 3) << 3))]);

    __builtin_amdgcn_s_setprio(1);
    #pragma unroll
    for (int df = 0; df < 4; ++df) {
      const int d = df * 16 + l15;
      o[df] = MFMA16(pa, ldsv8(&lVt[d * 32 + ((l4 * 8) ^ ((d & 3) << 3))]), o[df]);
    }
    __builtin_amdgcn_s_setprio(0);

    __syncthreads();   // drains vmcnt -> next pair's LDS data is ready
  }

  // merge parity partials via LDS (smem reuse), normalize, store
  float lrun[4] = {lr01.x, lr01.y, lr23.x, lr23.y};
  __syncthreads();
  float* xch = (float*)smem;
  float* slot = xch + rg * 1280;
  if (par) {
    #pragma unroll
    for (int df = 0; df < 4; ++df)
      *(f32x4*)&slot[(df * 64 + lane) * 4] = o[df];
    f32x4 lr;
    lr[0] = lrun[0]; lr[1] = lrun[1]; lr[2] = lrun[2]; lr[3] = lrun[3];
    *(f32x4*)&slot[1024 + lane * 4] = lr;
  }
  __syncthreads();
  if (!par) {
    #pragma unroll
    for (int df = 0; df < 4; ++df) {
      const f32x4 t = *(const f32x4*)&slot[(df * 64 + lane) * 4];
      o[df][0] += t[0]; o[df][1] += t[1]; o[df][2] += t[2]; o[df][3] += t[3];
    }
    const f32x4 lr = *(const f32x4*)&slot[1024 + lane * 4];
    #pragma unroll
    for (int e = 0; e < 4; ++e) {
      float ls = lrun[e] + lr[e];
      ls += __shfl_xor(ls, 1);
      ls += __shfl_xor(ls, 2);
      ls += __shfl_xor(ls, 4);
      ls += __shfl_xor(ls, 8);
      const float rl = __builtin_amdgcn_rcpf(ls);
      const int r = qr0 + l4 * 4 + e;
      #pragma unroll
      for (int df = 0; df < 4; ++df) {
        outg[(b * SS + r) * DM + h * HD + df * 16 + l15] = f2bf(o[df][e] * rl);
      }
    }
  }
}

// ---------------- launcher ----------------
extern "C" void kernel_launch(void* const* d_in, const int* in_sizes, int n_in,
                              void* d_out, int out_size, void* d_ws, size_t ws_size,
                              hipStream_t stream)
{
  const float* query   = (const float*)d_in[0];
  const float* key_in  = (const float*)d_in[1];
  const float* value   = (const float*)d_in[2];
  const int*   mask    = (const int*)d_in[3];
  const float* density = (const float*)d_in[4];
  const float* wq_r = (const float*)d_in[5];
  const float* wq_i = (const float*)d_in[6];
  const float* wq_j = (const float*)d_in[7];
  const float* wq_k = (const float*)d_in[8];
  const float* bq   = (const float*)d_in[9];
  const float* wk_r = (const float*)d_in[10];
  const float* wk_i = (const float*)d_in[11];
  const float* wk_j = (const float*)d_in[12];
  const float* wk_k = (const float*)d_in[13];
  const float* bk   = (const float*)d_in[14];
  const float* wv   = (const float*)d_in[15];
  const float* bv   = (const float*)d_in[16];
  const float* wo   = (const float*)d_in[17];
  const float* bo   = (const float*)d_in[18];
  const float* thrs = (const float*)d_in[19];
  const float* dm1w = (const float*)d_in[20];
  const float* dm1b = (const float*)d_in[21];
  const float* dm2w = (const float*)d_in[22];
  const float* dm2b = (const float*)d_in[23];

  char* ws = (char*)d_ws;
  unsigned short* Wq  = (unsigned short*)(ws + ((size_t)0 << 20));
  unsigned short* Wk  = (unsigned short*)(ws + ((size_t)2 << 20));
  unsigned short* Wv  = (unsigned short*)(ws + ((size_t)4 << 20));
  unsigned short* Wo  = (unsigned short*)(ws + ((size_t)6 << 20));
  unsigned short* qbf = (unsigned short*)(ws + ((size_t)8 << 20));
  unsigned short* kbf = (unsigned short*)(ws + ((size_t)16 << 20));
  unsigned short* vT  = (unsigned short*)(ws + ((size_t)24 << 20));
  unsigned short* att = (unsigned short*)(ws + ((size_t)32 << 20));
  float2* klim        = (float2*)(ws + ((size_t)40 << 20));
  int* amask          = (int*)(ws + ((size_t)40 << 20) + 65536);

  unsigned short* qcv = (unsigned short*)d_out;
  unsigned short* kcv = (unsigned short*)d_out + (size_t)MTOT * DM;
  unsigned short* vcv = att;

  hipMemsetAsync(amask, 0, 2 * sizeof(int), stream);
  prep_all<<<2576, 256, 0, stream>>>(
      wq_r, wq_i, wq_j, wq_k, wk_r, wk_i, wk_j, wk_k, wv, wo,
      Wq, Wk, Wv, Wo,
      query, key_in, value, qcv, kcv, vcv,
      density, dm1w, dm1b, dm2w, dm2b, thrs, mask, klim, amask);

  GemmArgs qkv;
  qkv.A[0] = qcv; qkv.W[0] = Wq; qkv.bias[0] = bq; qkv.out[0] = qbf; qkv.scale[0] = 0.25f; qkv.omode[0] = 0;
  qkv.A[1] = kcv; qkv.W[1] = Wk; qkv.bias[1] = bk; qkv.out[1] = kbf; qkv.scale[1] = 1.0f;  qkv.omode[1] = 0;
  qkv.A[2] = vcv; qkv.W[2] = Wv; qkv.bias[2] = bv; qkv.out[2] = vT;  qkv.scale[2] = 1.0f;  qkv.omode[2] = 1;
  gemm_bt<0><<<dim3(256, 3), 256, 0, stream>>>(qkv);

  attn_kernel<<<1024, 512, 0, stream>>>(qbf, kbf, vT, klim, mask, amask, att);

  GemmArgs og;
  og.A[0] = att; og.W[0] = Wo; og.bias[0] = bo; og.out[0] = d_out; og.scale[0] = 1.0f; og.omode[0] = 2;
  og.A[1] = att; og.W[1] = Wo; og.bias[1] = bo; og.out[1] = d_out; og.scale[1] = 1.0f; og.omode[1] = 2;
  og.A[2] = att; og.W[2] = Wo; og.bias[2] = bo; og.out[2] = d_out; og.scale[2] = 1.0f; og.omode[2] = 2;
  gemm_bt<1><<<dim3(256, 1), 256, 0, stream>>>(og);
}

// Round 11
// 175.996 us; speedup vs baseline: 1.0515x; 1.0258x over previous
//
#include <hip/hip_runtime.h>
#include <stdint.h>
#include <math.h>

#define BB 2
#define SS 2048
#define DM 1024
#define NH 16
#define HD 64
#define MTOT (BB*SS)

typedef __bf16 bf16x8 __attribute__((ext_vector_type(8)));
typedef float  f32x4  __attribute__((ext_vector_type(4)));
typedef float  f32x2  __attribute__((ext_vector_type(2)));
typedef uint32_t u32x4 __attribute__((ext_vector_type(4)));

__device__ __forceinline__ unsigned short f2bf(float f) {
  __bf16 h = (__bf16)f;                 // RNE; compiler packs to v_cvt_pk_bf16_f32
  return __builtin_bit_cast(unsigned short, h);
}

__device__ __forceinline__ bf16x8 ldsv8(const unsigned short* p) {
  return __builtin_bit_cast(bf16x8, *(const u32x4*)p);
}

__device__ __forceinline__ void gl16(const void* g, void* l) {
  __builtin_amdgcn_global_load_lds(
      (const __attribute__((address_space(1))) uint32_t*)g,
      (__attribute__((address_space(3))) uint32_t*)l, 16, 0, 0);
}

#define MFMA16(a,b,c) __builtin_amdgcn_mfma_f32_16x16x32_bf16((a),(b),(c),0,0,0)

// gate/softmax constants
#define C_NEG5L2E  (-7.213475204444817f)   // -5*log2(e)
#define C_L2E      (1.4426950408889634f)   // log2(e)
#define C_18L2E    (25.968510736001341f)   // 18*log2(e)

// packed (v_pk_*) gate evaluation for an e-pair: returns p = exp(mod-18), accumulates into lr
__device__ __forceinline__ f32x2 gate_pk(f32x2 s2, float kth, f32x2& lr) {
  s2 = __builtin_elementwise_min(__builtin_elementwise_max(s2, (f32x2){-6.f,-6.f}), (f32x2){6.f,6.f});
  const f32x2 targ = __builtin_elementwise_fma(s2, (f32x2){C_NEG5L2E, C_NEG5L2E}, (f32x2){kth, kth});
  f32x2 t;
  t.x = __builtin_amdgcn_exp2f(targ.x);
  t.y = __builtin_amdgcn_exp2f(targ.y);
  const f32x2 den = t + (f32x2){1.f, 1.f};
  f32x2 g;
  g.x = __builtin_amdgcn_rcpf(den.x);
  g.y = __builtin_amdgcn_rcpf(den.y);
  const f32x2 md = __builtin_elementwise_fma(s2 + s2, g, s2);       // s*(1+2g)
  const f32x2 pa = __builtin_elementwise_fma(md, (f32x2){C_L2E, C_L2E}, (f32x2){-C_18L2E, -C_18L2E});
  f32x2 p;
  p.x = __builtin_amdgcn_exp2f(pa.x);
  p.y = __builtin_amdgcn_exp2f(pa.y);
  lr += p;
  return p;
}

// ---------------- fused prep: quaternion weights + activation cvt + thresholds ----------------
// blocks [0,512): prep_w (8 elem/thread over 1M); [512,2560): cvt (8/thread over 4.19M); [2560,2576): thr.
__global__ __launch_bounds__(256) void prep_all(
    const float* __restrict__ wqr, const float* __restrict__ wqi,
    const float* __restrict__ wqj, const float* __restrict__ wqk,
    const float* __restrict__ wkr, const float* __restrict__ wki,
    const float* __restrict__ wkj, const float* __restrict__ wkk,
    const float* __restrict__ wv,  const float* __restrict__ wo,
    unsigned short* __restrict__ Wq, unsigned short* __restrict__ Wk,
    unsigned short* __restrict__ Wv, unsigned short* __restrict__ Wo,
    const float* __restrict__ query, const float* __restrict__ key_in,
    const float* __restrict__ value,
    unsigned short* __restrict__ qcv, unsigned short* __restrict__ kcv,
    unsigned short* __restrict__ vcv,
    const float* __restrict__ density, const float* __restrict__ dm1w,
    const float* __restrict__ dm1b, const float* __restrict__ dm2w,
    const float* __restrict__ dm2b, const float* __restrict__ thr_s,
    const int* __restrict__ mask, float2* __restrict__ klim,
    int* __restrict__ amask)
{
  const int bid = blockIdx.x;
  if (bid < 512) {
    const int idx = (bid * 256 + threadIdx.x) * 8;      // 8 consecutive elems, same row/block
    const int o = idx >> 10, i = idx & 1023;
    const int br = o >> 8, bc = i >> 8;
    const int ro = o & 255, ci = i & 255;
    const int comp[4][4] = {{0,1,2,3},{1,0,3,2},{2,3,0,1},{3,2,1,0}};
    const float sgn[4][4] = {{1.f,-1.f,-1.f,-1.f},{1.f,1.f,-1.f,1.f},{1.f,1.f,1.f,-1.f},{1.f,-1.f,1.f,1.f}};
    const float* pq[4] = {wqr, wqi, wqj, wqk};
    const float* pk[4] = {wkr, wki, wkj, wkk};
    const int c_ = comp[br][bc];
    const float s_ = sgn[br][bc];
    const float* qsrc = pq[c_] + ro * 256 + ci;
    const float* ksrc = pk[c_] + ro * 256 + ci;
    {
      const float4 f0 = *(const float4*)qsrc;
      const float4 f1 = *(const float4*)(qsrc + 4);
      union { unsigned short us[8]; u32x4 v; } t;
      t.us[0]=f2bf(s_*f0.x); t.us[1]=f2bf(s_*f0.y); t.us[2]=f2bf(s_*f0.z); t.us[3]=f2bf(s_*f0.w);
      t.us[4]=f2bf(s_*f1.x); t.us[5]=f2bf(s_*f1.y); t.us[6]=f2bf(s_*f1.z); t.us[7]=f2bf(s_*f1.w);
      *(u32x4*)(Wq + idx) = t.v;
    }
    {
      const float4 f0 = *(const float4*)ksrc;
      const float4 f1 = *(const float4*)(ksrc + 4);
      union { unsigned short us[8]; u32x4 v; } t;
      t.us[0]=f2bf(s_*f0.x); t.us[1]=f2bf(s_*f0.y); t.us[2]=f2bf(s_*f0.z); t.us[3]=f2bf(s_*f0.w);
      t.us[4]=f2bf(s_*f1.x); t.us[5]=f2bf(s_*f1.y); t.us[6]=f2bf(s_*f1.z); t.us[7]=f2bf(s_*f1.w);
      *(u32x4*)(Wk + idx) = t.v;
    }
    {
      const float4 f0 = *(const float4*)(wv + idx);
      const float4 f1 = *(const float4*)(wv + idx + 4);
      union { unsigned short us[8]; u32x4 v; } t;
      t.us[0]=f2bf(f0.x); t.us[1]=f2bf(f0.y); t.us[2]=f2bf(f0.z); t.us[3]=f2bf(f0.w);
      t.us[4]=f2bf(f1.x); t.us[5]=f2bf(f1.y); t.us[6]=f2bf(f1.z); t.us[7]=f2bf(f1.w);
      *(u32x4*)(Wv + idx) = t.v;
    }
    {
      const float4 f0 = *(const float4*)(wo + idx);
      const float4 f1 = *(const float4*)(wo + idx + 4);
      union { unsigned short us[8]; u32x4 v; } t;
      t.us[0]=f2bf(f0.x); t.us[1]=f2bf(f0.y); t.us[2]=f2bf(f0.z); t.us[3]=f2bf(f0.w);
      t.us[4]=f2bf(f1.x); t.us[5]=f2bf(f1.y); t.us[6]=f2bf(f1.z); t.us[7]=f2bf(f1.w);
      *(u32x4*)(Wo + idx) = t.v;
    }
  } else if (bid < 2560) {
    const int i8 = ((bid - 512) * 256 + threadIdx.x) * 8;
    {
      const float4 f0 = *(const float4*)(query + i8);
      const float4 f1 = *(const float4*)(query + i8 + 4);
      union { unsigned short us[8]; u32x4 v; } t;
      t.us[0]=f2bf(f0.x); t.us[1]=f2bf(f0.y); t.us[2]=f2bf(f0.z); t.us[3]=f2bf(f0.w);
      t.us[4]=f2bf(f1.x); t.us[5]=f2bf(f1.y); t.us[6]=f2bf(f1.z); t.us[7]=f2bf(f1.w);
      *(u32x4*)(qcv + i8) = t.v;
    }
    {
      const float4 f0 = *(const float4*)(key_in + i8);
      const float4 f1 = *(const float4*)(key_in + i8 + 4);
      union { unsigned short us[8]; u32x4 v; } t;
      t.us[0]=f2bf(f0.x); t.us[1]=f2bf(f0.y); t.us[2]=f2bf(f0.z); t.us[3]=f2bf(f0.w);
      t.us[4]=f2bf(f1.x); t.us[5]=f2bf(f1.y); t.us[6]=f2bf(f1.z); t.us[7]=f2bf(f1.w);
      *(u32x4*)(kcv + i8) = t.v;
    }
    {
      const float4 f0 = *(const float4*)(value + i8);
      const float4 f1 = *(const float4*)(value + i8 + 4);
      union { unsigned short us[8]; u32x4 v; } t;
      t.us[0]=f2bf(f0.x); t.us[1]=f2bf(f0.y); t.us[2]=f2bf(f0.z); t.us[3]=f2bf(f0.w);
      t.us[4]=f2bf(f1.x); t.us[5]=f2bf(f1.y); t.us[6]=f2bf(f1.z); t.us[7]=f2bf(f1.w);
      *(u32x4*)(vcv + i8) = t.v;
    }
  } else {
    const int i = (bid - 2560) * 256 + threadIdx.x;  // over B*S = 4096
    if (i >= BB * SS) return;
    const float x0 = density[i*3+0], x1 = density[i*3+1], x2 = density[i*3+2];
    const float base = log1pf(expf(thr_s[0]));     // softplus
    float acc = dm2b[0];
    #pragma unroll
    for (int j = 0; j < 16; ++j) {
      const float hj = dm1w[j*3+0]*x0 + dm1w[j*3+1]*x1 + dm1w[j*3+2]*x2 + dm1b[j];
      const float ge = 0.5f * hj * (1.0f + erff(hj * 0.70710678118654752f)); // exact gelu
      acc += dm2w[j] * ge;
    }
    const float thr = base + 0.1f * acc;
    const int mk = mask[i];
    klim[i] = make_float2(thr * (-C_NEG5L2E),          // +5*log2e*thr (exp2 arg offset)
                          mk ? 1e30f : -30.0f);        // mask limit for min
    const unsigned long long any = __ballot(mk == 0);
    if ((threadIdx.x & 63) == 0 && any)
      atomicOr(&amask[i >> 11], 1);                    // per-batch "has masked rows" flag
  }
}

// ---------------- GEMM: C(M=4096,N=1024) = A(M,K=1024) @ W(N,K)^T + bias ----------------
struct GemmArgs {
  const unsigned short* A[3];
  const unsigned short* W[3];
  const float* bias[3];
  void* out[3];
  float scale[3];
  int omode[3];
};

template<int DB>
__global__ __launch_bounds__(256) void gemm_bt(GemmArgs args)
{
  __shared__ __align__(16) unsigned short lA[DB + 1][128*64];
  __shared__ __align__(16) unsigned short lB[DB + 1][128*64];
  const int z = blockIdx.y;
  const int tid = threadIdx.x;
  const int wid = tid >> 6, lane = tid & 63;
  const int l15 = lane & 15, l4 = lane >> 4;
  const int bm = blockIdx.x & 31, bn = blockIdx.x >> 5;   // XCD-aware decode
  const int row0 = bm * 128, col0 = bn * 128;
  const int wm = (wid >> 1) * 64, wn = (wid & 1) * 64;

  const unsigned short* gA[4];
  const unsigned short* gB[4];
  #pragma unroll
  for (int i = 0; i < 4; ++i) {
    const int c = (wid * 4 + i) * 64 + lane;
    const int r = c >> 3, jx = c & 7, j = jx ^ (r & 7);
    gA[i] = args.A[z] + (row0 + r) * 1024 + j * 8;
    gB[i] = args.W[z] + (col0 + r) * 1024 + j * 8;
  }

  f32x4 acc[4][4];
  #pragma unroll
  for (int i = 0; i < 4; ++i)
    #pragma unroll
    for (int j = 0; j < 4; ++j) acc[i][j] = (f32x4){0.f,0.f,0.f,0.f};

  #pragma unroll
  for (int i = 0; i < 4; ++i) {
    gl16(gA[i], &lA[0][(wid * 4 + i) * 512]);
    gl16(gB[i], &lB[0][(wid * 4 + i) * 512]);
  }
  if (DB) __syncthreads();

  for (int kt = 0; kt < 16; ++kt) {
    const int cb = DB ? (kt & 1) : 0;
    if (DB) {
      if (kt < 15) {
        const int nb = cb ^ 1, k0 = (kt + 1) * 64;
        #pragma unroll
        for (int i = 0; i < 4; ++i) {
          gl16(gA[i] + k0, &lA[nb][(wid * 4 + i) * 512]);
          gl16(gB[i] + k0, &lB[nb][(wid * 4 + i) * 512]);
        }
      }
    } else {
      if (kt > 0) {
        const int k0 = kt * 64;
        #pragma unroll
        for (int i = 0; i < 4; ++i) {
          gl16(gA[i] + k0, &lA[0][(wid * 4 + i) * 512]);
          gl16(gB[i] + k0, &lB[0][(wid * 4 + i) * 512]);
        }
      }
      __syncthreads();
    }
    #pragma unroll
    for (int kk = 0; kk < 2; ++kk) {
      const int kl = kk * 32 + l4 * 8;
      bf16x8 af[4], bfb[4];
      #pragma unroll
      for (int mi = 0; mi < 4; ++mi) {
        const int r = wm + mi * 16 + l15;
        af[mi] = ldsv8(&lA[cb][r * 64 + (kl ^ ((r & 7) << 3))]);
      }
      #pragma unroll
      for (int nj = 0; nj < 4; ++nj) {
        const int r = wn + nj * 16 + l15;
        bfb[nj] = ldsv8(&lB[cb][r * 64 + (kl ^ ((r & 7) << 3))]);
      }
      #pragma unroll
      for (int mi = 0; mi < 4; ++mi)
        #pragma unroll
        for (int nj = 0; nj < 4; ++nj)
          acc[mi][nj] = MFMA16(af[mi], bfb[nj], acc[mi][nj]);
    }
    __syncthreads();
  }

  const int om = args.omode[z];
  const float sc = args.scale[z];
  void* Cptr = args.out[z];
  #pragma unroll
  for (int nj = 0; nj < 4; ++nj) {
    const int c = col0 + wn + nj * 16 + l15;
    const float bv_ = args.bias[z][c];
    #pragma unroll
    for (int mi = 0; mi < 4; ++mi) {
      const int rb = row0 + wm + mi * 16 + l4 * 4;
      #pragma unroll
      for (int e = 0; e < 4; ++e) {
        const float val = (acc[mi][nj][e] + bv_) * sc;
        const int r = rb + e;
        if (om == 0) {
          ((unsigned short*)Cptr)[r * 1024 + c] = f2bf(val);
        } else if (om == 2) {
          ((float*)Cptr)[r * 1024 + c] = val;
        } else {
          const int h = c >> 6, d = c & 63, b = r >> 11, s = r & 2047;
          ((unsigned short*)Cptr)[((h * BB + b) * HD + d) * SS + s] = f2bf(val);
        }
      }
    }
  }
}

// ---------------- flash attention: split-K wave pairs with K/V-fragment reuse ----------------
// 256 threads = 4 waves = 2 row-groups(32 q-rows each) x 2 key-parities.
// Each wave computes 32 q-rows as two 16-row sub-groups SHARING one set of K/V
// fragment reads -> block LDS traffic per tile-step drops 72->40 b128 (LDS-pipe
// was ~83% busy in R10 - the measured bottleneck). Fixed-max softmax unchanged.
__global__ __launch_bounds__(256, 4) void attn_kernel(
    const unsigned short* __restrict__ qg, const unsigned short* __restrict__ kg,
    const unsigned short* __restrict__ vT, const float2* __restrict__ klim,
    const int* __restrict__ mask, const int* __restrict__ amask,
    unsigned short* __restrict__ outg)
{
  __shared__ __align__(16) unsigned short smem[20480];   // 40 KB
  unsigned char* sb = (unsigned char*)smem;
  unsigned short* lK = smem;            // [buf2][par2][32 keys][64 hd]
  unsigned short* lV = smem + 8192;     // [buf2][par2][64 d][32 keys]
  unsigned short* lP = smem + 16384;    // [wave4][sr2][16 rows][32 keys]

  const int tid = threadIdx.x;
  const int wid = tid >> 6, lane = tid & 63;
  const int l15 = lane & 15, l4 = lane >> 4;
  const int rg = wid >> 1, par = wid & 1;
  const int hb = blockIdx.x & 31, qb = blockIdx.x >> 5;  // XCD: same (h,b) -> same XCD
  const int h = hb >> 1, b = hb & 1;
  const int qr0 = qb * 64 + rg * 32;

  const unsigned short* kbase = kg + (b * SS) * DM + h * HD;
  const unsigned short* vbase = vT + ((h * BB + b) * HD) * SS;
  const float2* klimb = klim + b * SS;
  const int clean = (amask[b] == 0);

  // global_load_lds source mapping (inverse of the XOR-swizzled LDS layout).
  // K parity tile (4KB): byte w*1024 + l*16 -> row rho=w*8+(l>>3), chunk (l&7)^((rho>>1)&7)
  const int krho = wid * 8 + (lane >> 3);
  const int kc   = (lane & 7) ^ ((krho >> 1) & 7);
  const unsigned short* ksrc0 = kbase + (size_t)krho * DM + kc * 8;          // parity 0 keys
  const unsigned short* ksrc1 = kbase + (size_t)(32 + krho) * DM + kc * 8;   // parity 1 keys
  // V parity tile (4KB): byte w*1024 + l*16 -> d=w*16+(l>>2), chunk (l&3)^(d&3)
  const int vd_  = wid * 16 + (lane >> 2);
  const int vc   = (lane & 3) ^ (vd_ & 3);
  const unsigned short* vsrc0 = vbase + (size_t)vd_ * SS + vc * 8;
  const unsigned short* vsrc1 = vbase + (size_t)vd_ * SS + 32 + vc * 8;
  unsigned char* kd0 = sb + wid * 1024;                   // + cur*8192
  unsigned char* kd1 = sb + 4096 + wid * 1024;
  unsigned char* vd0 = sb + 16384 + wid * 1024;
  unsigned char* vd1 = sb + 16384 + 4096 + wid * 1024;

  // Q fragments: 2 sub-rowgroups x 2 k-halves (A-frag: row=lane%16, k=(lane>>4)*8)
  bf16x8 aq[2][2];
  #pragma unroll
  for (int sr = 0; sr < 2; ++sr) {
    const unsigned short* qs = qg + (b * SS + qr0 + sr * 16 + l15) * DM + h * HD + l4 * 8;
    aq[sr][0] = __builtin_bit_cast(bf16x8, *(const u32x4*)qs);
    aq[sr][1] = __builtin_bit_cast(bf16x8, *(const u32x4*)(qs + 32));
  }
  float limq[2][4];
  if (!clean) {
    #pragma unroll
    for (int sr = 0; sr < 2; ++sr)
      #pragma unroll
      for (int e = 0; e < 4; ++e)
        limq[sr][e] = mask[b * SS + qr0 + sr * 16 + l4 * 4 + e] ? 1e30f : -30.0f;
  }

  f32x2 lr01[2] = {{0.f,0.f},{0.f,0.f}}, lr23[2] = {{0.f,0.f},{0.f,0.f}};
  f32x4 o[2][4];
  #pragma unroll
  for (int sr = 0; sr < 2; ++sr)
    #pragma unroll
    for (int d = 0; d < 4; ++d) o[sr][d] = (f32x4){0.f,0.f,0.f,0.f};

  unsigned short* lPw = lP + wid * 1024;

  // prologue: stage pair 0
  gl16(ksrc0, kd0);
  gl16(ksrc1, kd1);
  gl16(vsrc0, vd0);
  gl16(vsrc1, vd1);
  __syncthreads();

  #pragma unroll 2
  for (int pr = 0; pr < 32; ++pr) {
    const int cur = pr & 1;
    const unsigned short* lKt = lK + cur * 4096 + par * 2048;
    const unsigned short* lVt = lV + cur * 4096 + par * 2048;
    const int n0 = pr * 64 + par * 32;

    // issue async staging of the next pair into the other buffer
    if (pr < 31) {
      const int co = (cur ^ 1) * 8192;
      const size_t ko = (size_t)(pr + 1) * 64 * DM;
      gl16(ksrc0 + ko, kd0 + co);
      gl16(ksrc1 + ko, kd1 + co);
      gl16(vsrc0 + (pr + 1) * 64, vd0 + co);
      gl16(vsrc1 + (pr + 1) * 64, vd1 + co);
    }

    const float4 klA = *(const float4*)(klimb + n0 + 2 * l15);   // keys 2l15, 2l15+1

    // S = Q @ K^T : key = 2*l15 + cf; K fragments read ONCE, reused for both sr
    f32x4 sv[2][2];
    __builtin_amdgcn_s_setprio(1);
    #pragma unroll
    for (int cf = 0; cf < 2; ++cf) {
      const int r = 2 * l15 + cf;
      const bf16x8 kf0 = ldsv8(&lKt[r * 64 + ((l4 * 8) ^ ((l15 & 7) << 3))]);
      const bf16x8 kf1 = ldsv8(&lKt[r * 64 + ((32 + l4 * 8) ^ ((l15 & 7) << 3))]);
      #pragma unroll
      for (int sr = 0; sr < 2; ++sr) {
        f32x4 a = (f32x4){0.f,0.f,0.f,0.f};
        a = MFMA16(aq[sr][0], kf0, a);
        a = MFMA16(aq[sr][1], kf1, a);
        sv[sr][cf] = a;
      }
    }
    __builtin_amdgcn_s_setprio(0);

    // spike gate + mask + fixed-max softmax numerator (packed f32)
    f32x2 p01[2][2], p23[2][2];                    // [sr][cf]
    if (clean) {
      #pragma unroll
      for (int sr = 0; sr < 2; ++sr)
        #pragma unroll
        for (int cf = 0; cf < 2; ++cf) {
          const float kth = cf ? klA.z : klA.x;
          p01[sr][cf] = gate_pk((f32x2){sv[sr][cf][0], sv[sr][cf][1]}, kth, lr01[sr]);
          p23[sr][cf] = gate_pk((f32x2){sv[sr][cf][2], sv[sr][cf][3]}, kth, lr23[sr]);
        }
    } else {
      #pragma unroll
      for (int sr = 0; sr < 2; ++sr)
        #pragma unroll
        for (int cf = 0; cf < 2; ++cf) {
          const float kth = cf ? klA.z : klA.x;
          const float klm = cf ? klA.w : klA.y;
          float pe[4];
          #pragma unroll
          for (int e = 0; e < 4; ++e) {
            float s = fminf(fmaxf(sv[sr][cf][e], -6.f), 6.f);
            const float t = __builtin_amdgcn_exp2f(fmaf(s, C_NEG5L2E, kth));
            const float g = __builtin_amdgcn_rcpf(1.f + t);
            float md = fmaf(s + s, g, s);
            md = fminf(md, fminf(klm, limq[sr][e]));            // mask -> -30
            pe[e] = __builtin_amdgcn_exp2f(fmaf(md, C_L2E, -C_18L2E));
          }
          p01[sr][cf] = (f32x2){pe[0], pe[1]};
          p23[sr][cf] = (f32x2){pe[2], pe[3]};
          lr01[sr] += p01[sr][cf];
          lr23[sr] += p23[sr][cf];
        }
    }

    // P -> per-wave LDS: packed pair writes (keys 2l15, 2l15+1), both sub-groups
    #pragma unroll
    for (int sr = 0; sr < 2; ++sr)
      #pragma unroll
      for (int e = 0; e < 4; ++e) {
        const int rr = l4 * 4 + e;
        const float pa_ = (e < 2) ? p01[sr][0][e] : p23[sr][0][e - 2];
        const float pb_ = (e < 2) ? p01[sr][1][e] : p23[sr][1][e - 2];
        union { unsigned short us[2]; unsigned int u; } pk2;
        pk2.us[0] = f2bf(pa_);
        pk2.us[1] = f2bf(pb_);
        *(unsigned int*)&lPw[sr * 512 + rr * 32 + ((2 * l15) ^ ((rr & 3) << 3))] = pk2.u;
      }
    asm volatile("s_waitcnt lgkmcnt(0)" ::: "memory");
    __builtin_amdgcn_sched_barrier(0);

    const bf16x8 pa0 = ldsv8(&lPw[l15 * 32 + ((l4 * 8) ^ ((l15 & 3) << 3))]);
    const bf16x8 pa1 = ldsv8(&lPw[512 + l15 * 32 + ((l4 * 8) ^ ((l15 & 3) << 3))]);

    // PV: V fragments read ONCE, reused for both sr
    __builtin_amdgcn_s_setprio(1);
    #pragma unroll
    for (int df = 0; df < 4; ++df) {
      const int d = df * 16 + l15;
      const bf16x8 vf = ldsv8(&lVt[d * 32 + ((l4 * 8) ^ ((d & 3) << 3))]);
      o[0][df] = MFMA16(pa0, vf, o[0][df]);
      o[1][df] = MFMA16(pa1, vf, o[1][df]);
    }
    __builtin_amdgcn_s_setprio(0);

    __syncthreads();   // drains vmcnt -> next pair's LDS data is ready
  }

  // merge parity partials via LDS (smem reuse: 2 rg x 2560 floats = 20KB), normalize, store
  __syncthreads();
  float* xch = (float*)smem;
  float* slot = xch + rg * 2560;
  if (par) {
    #pragma unroll
    for (int sr = 0; sr < 2; ++sr) {
      #pragma unroll
      for (int df = 0; df < 4; ++df)
        *(f32x4*)&slot[((sr * 4 + df) * 64 + lane) * 4] = o[sr][df];
      f32x4 lr;
      lr[0] = lr01[sr].x; lr[1] = lr01[sr].y; lr[2] = lr23[sr].x; lr[3] = lr23[sr].y;
      *(f32x4*)&slot[2048 + (sr * 64 + lane) * 4] = lr;
    }
  }
  __syncthreads();
  if (!par) {
    #pragma unroll
    for (int sr = 0; sr < 2; ++sr) {
      #pragma unroll
      for (int df = 0; df < 4; ++df) {
        const f32x4 t = *(const f32x4*)&slot[((sr * 4 + df) * 64 + lane) * 4];
        o[sr][df][0] += t[0]; o[sr][df][1] += t[1]; o[sr][df][2] += t[2]; o[sr][df][3] += t[3];
      }
      const f32x4 lrq = *(const f32x4*)&slot[2048 + (sr * 64 + lane) * 4];
      const float lrun[4] = {lr01[sr].x, lr01[sr].y, lr23[sr].x, lr23[sr].y};
      #pragma unroll
      for (int e = 0; e < 4; ++e) {
        float ls = lrun[e] + lrq[e];
        ls += __shfl_xor(ls, 1);
        ls += __shfl_xor(ls, 2);
        ls += __shfl_xor(ls, 4);
        ls += __shfl_xor(ls, 8);
        const float rl = __builtin_amdgcn_rcpf(ls);
        const int r = qr0 + sr * 16 + l4 * 4 + e;
        #pragma unroll
        for (int df = 0; df < 4; ++df) {
          outg[(b * SS + r) * DM + h * HD + df * 16 + l15] = f2bf(o[sr][df][e] * rl);
        }
      }
    }
  }
}

// ---------------- launcher ----------------
extern "C" void kernel_launch(void* const* d_in, const int* in_sizes, int n_in,
                              void* d_out, int out_size, void* d_ws, size_t ws_size,
                              hipStream_t stream)
{
  const float* query   = (const float*)d_in[0];
  const float* key_in  = (const float*)d_in[1];
  const float* value   = (const float*)d_in[2];
  const int*   mask    = (const int*)d_in[3];
  const float* density = (const float*)d_in[4];
  const float* wq_r = (const float*)d_in[5];
  const float* wq_i = (const float*)d_in[6];
  const float* wq_j = (const float*)d_in[7];
  const float* wq_k = (const float*)d_in[8];
  const float* bq   = (const float*)d_in[9];
  const float* wk_r = (const float*)d_in[10];
  const float* wk_i = (const float*)d_in[11];
  const float* wk_j = (const float*)d_in[12];
  const float* wk_k = (const float*)d_in[13];
  const float* bk   = (const float*)d_in[14];
  const float* wv   = (const float*)d_in[15];
  const float* bv   = (const float*)d_in[16];
  const float* wo   = (const float*)d_in[17];
  const float* bo   = (const float*)d_in[18];
  const float* thrs = (const float*)d_in[19];
  const float* dm1w = (const float*)d_in[20];
  const float* dm1b = (const float*)d_in[21];
  const float* dm2w = (const float*)d_in[22];
  const float* dm2b = (const float*)d_in[23];

  char* ws = (char*)d_ws;
  unsigned short* Wq  = (unsigned short*)(ws + ((size_t)0 << 20));
  unsigned short* Wk  = (unsigned short*)(ws + ((size_t)2 << 20));
  unsigned short* Wv  = (unsigned short*)(ws + ((size_t)4 << 20));
  unsigned short* Wo  = (unsigned short*)(ws + ((size_t)6 << 20));
  unsigned short* qbf = (unsigned short*)(ws + ((size_t)8 << 20));
  unsigned short* kbf = (unsigned short*)(ws + ((size_t)16 << 20));
  unsigned short* vT  = (unsigned short*)(ws + ((size_t)24 << 20));
  unsigned short* att = (unsigned short*)(ws + ((size_t)32 << 20));
  float2* klim        = (float2*)(ws + ((size_t)40 << 20));
  int* amask          = (int*)(ws + ((size_t)40 << 20) + 65536);

  unsigned short* qcv = (unsigned short*)d_out;
  unsigned short* kcv = (unsigned short*)d_out + (size_t)MTOT * DM;
  unsigned short* vcv = att;

  hipMemsetAsync(amask, 0, 2 * sizeof(int), stream);
  prep_all<<<2576, 256, 0, stream>>>(
      wq_r, wq_i, wq_j, wq_k, wk_r, wk_i, wk_j, wk_k, wv, wo,
      Wq, Wk, Wv, Wo,
      query, key_in, value, qcv, kcv, vcv,
      density, dm1w, dm1b, dm2w, dm2b, thrs, mask, klim, amask);

  GemmArgs qkv;
  qkv.A[0] = qcv; qkv.W[0] = Wq; qkv.bias[0] = bq; qkv.out[0] = qbf; qkv.scale[0] = 0.25f; qkv.omode[0] = 0;
  qkv.A[1] = kcv; qkv.W[1] = Wk; qkv.bias[1] = bk; qkv.out[1] = kbf; qkv.scale[1] = 1.0f;  qkv.omode[1] = 0;
  qkv.A[2] = vcv; qkv.W[2] = Wv; qkv.bias[2] = bv; qkv.out[2] = vT;  qkv.scale[2] = 1.0f;  qkv.omode[2] = 1;
  gemm_bt<0><<<dim3(256, 3), 256, 0, stream>>>(qkv);

  attn_kernel<<<1024, 256, 0, stream>>>(qbf, kbf, vT, klim, mask, amask, att);

  GemmArgs og;
  og.A[0] = att; og.W[0] = Wo; og.bias[0] = bo; og.out[0] = d_out; og.scale[0] = 1.0f; og.omode[0] = 2;
  og.A[1] = att; og.W[1] = Wo; og.bias[1] = bo; og.out[1] = d_out; og.scale[1] = 1.0f; og.omode[1] = 2;
  og.A[2] = att; og.W[2] = Wo; og.bias[2] = bo; og.out[2] = d_out; og.scale[2] = 1.0f; og.omode[2] = 2;
  gemm_bt<1><<<dim3(256, 1), 256, 0, stream>>>(og);
}